// Round 11
// baseline (209.436 us; speedup 1.0000x reference)
//
#include <hip/hip_runtime.h>

typedef _Float16 f16;
typedef __fp16 h16x2 __attribute__((ext_vector_type(2)));
typedef _Float16 f16x8 __attribute__((ext_vector_type(8)));
typedef float f32x4 __attribute__((ext_vector_type(4)));

#define H_ 12
#define B_ 4
#define S_ 2048
#define DM 768
#define DK 64
#define HBSD ((size_t)H_ * B_ * S_ * DK)

__device__ __forceinline__ f16 f2h(float f) { return (f16)f; }
__device__ __forceinline__ float max3f(float a, float b, float c) {
  return fmaxf(fmaxf(a, b), c);  // clang fuses to v_max3_f32
}

// async global->LDS, 16B per lane. LDS dest must be wave-uniform base + lane*16.
__device__ __forceinline__ void gl_lds16(const f16* g, f16* l) {
  __builtin_amdgcn_global_load_lds(
      (const __attribute__((address_space(1))) void*)g,
      (__attribute__((address_space(3))) void*)l, 16, 0, 0);
}

// ---------------- prep kernels ----------------

__global__ __launch_bounds__(256) void cast_x_kernel(const float* __restrict__ x,
                                                     f16* __restrict__ xb, int n4) {
  int i = blockIdx.x * 256 + threadIdx.x;
  if (i < n4) {
    float4 v = ((const float4*)x)[i];
    union { f16 h[4]; uint2 u; } pk;
    pk.h[0] = f2h(v.x); pk.h[1] = f2h(v.y); pk.h[2] = f2h(v.z); pk.h[3] = f2h(v.w);
    ((uint2*)xb)[i] = pk.u;
  }
}

// Merged weight transpose+cast (one launch):
// which<3: W_{which}[h][m][c] -> Wt[(which*768 + h*64 + c)][m]
// which==3: WO[n][d] -> Wot[d][n]
__global__ __launch_bounds__(256) void tcast_w_kernel(const float* __restrict__ WQ,
                                                      const float* __restrict__ WK,
                                                      const float* __restrict__ WV,
                                                      const float* __restrict__ WO,
                                                      f16* __restrict__ Wt,
                                                      f16* __restrict__ Wot) {
  __shared__ float L[64][65];
  const int which = blockIdx.y;
  const int t = threadIdx.x;
  const int lr = t >> 2, lc = (t & 3) * 16;
  const float* ip;
  if (which < 3) {
    const int m0 = blockIdx.x * 64, h = blockIdx.z;
    const float* in = (which == 0 ? WQ : which == 1 ? WK : WV) + (size_t)h * DM * DK;
    ip = in + (size_t)(m0 + lr) * DK + lc;
  } else {
    const int n0 = blockIdx.x * 64, d0 = blockIdx.z * 64;
    ip = WO + (size_t)(n0 + lr) * DM + d0 + lc;
  }
#pragma unroll
  for (int i = 0; i < 4; i++) {
    float4 v = *(const float4*)(ip + i * 4);
    L[lr][lc + i * 4 + 0] = v.x;
    L[lr][lc + i * 4 + 1] = v.y;
    L[lr][lc + i * 4 + 2] = v.z;
    L[lr][lc + i * 4 + 3] = v.w;
  }
  __syncthreads();
  const int oc = t >> 2, om = (t & 3) * 16;
  union { f16 hh[16]; uint4 u[2]; } pk;
#pragma unroll
  for (int jx = 0; jx < 16; jx++) pk.hh[jx] = f2h(L[om + jx][oc]);
  f16* op;
  if (which < 3) {
    const int m0 = blockIdx.x * 64, h = blockIdx.z;
    op = Wt + ((size_t)which * DM + h * DK + oc) * DM + m0 + om;
  } else {
    const int n0 = blockIdx.x * 64, d0 = blockIdx.z * 64;
    op = Wot + (size_t)(d0 + oc) * DM + n0 + om;
  }
  *(uint4*)op = pk.u[0];
  *(uint4*)(op + 8) = pk.u[1];
}

// ---------------- GEMM, BK=64 2-slab: C[M,N] = A[M,K] * Bt[N,K]^T ----------------
// LDS layout per matrix: [slab s][row 128][32 cols]; slab stride 128*32 = 4096.
// Bank-conflict fix: XOR-swizzle byte bits 4-5 with row bits 1-2 (source-pre-swizzle
// + swizzled read quad qsw). XCD swizzle (T1) for L2 locality.
// Q outputs pre-scaled by log2(e)/8.
// v16: ALL MODE==1 epilogues now go through an LDS transpose reusing the 32KB
// staging buffer. V blocks (R8, measured ~6us): scatter was 8B/4KB-stride.
// Q/K blocks (new): direct stores were 64x 2B scalars/lane, 32B-per-quad chunks
// = 50% sector efficiency (~50MB traffic for 25.2MB useful) — now 8x f16x8
// fully-dense 128B row-chunks per thread.
template <int MODE>
__global__ __launch_bounds__(256) void gemm_bt_kernel(const f16* __restrict__ A,
                                                      const f16* __restrict__ Bt,
                                                      float* __restrict__ Cf,
                                                      f16* __restrict__ Cq,
                                                      f16* __restrict__ Vt, int N) {
  constexpr int K = 768;
  __shared__ __align__(16) f16 SH[16384];  // As | Bs; reused as transpose buffer
  f16* As = SH;
  f16* Bs = SH + 8192;
  const int t = threadIdx.x;
  const int nbx = gridDim.x, nwg = nbx * gridDim.y;
  const int d = blockIdx.y * nbx + blockIdx.x;
  const int wg = (d & 7) * (nwg >> 3) + (d >> 3);  // bijective (nwg%8==0)
  const int m0 = (wg / nbx) * 128, n0 = (wg % nbx) * 128;
  const int lane = t & 63, wave = t >> 6;
  const int l15 = lane & 15, quad = lane >> 4;
  const int qsw = quad ^ ((l15 >> 1) & 3);  // swizzled read quad
  const int m_off = (wave & 1) * 64, n_off = (wave >> 1) * 64;
  const int r0 = t >> 2, ko = ((t & 3) ^ ((t >> 3) & 3)) * 8;  // swizzled source col
  const f16* Ag0 = A + (size_t)(m0 + r0) * K + ko;
  const f16* Ag1 = A + (size_t)(m0 + r0 + 64) * K + ko;
  const f16* Bg0 = Bt + (size_t)(n0 + r0) * K + ko;
  const f16* Bg1 = Bt + (size_t)(n0 + r0 + 64) * K + ko;

  f32x4 acc[4][4];
  const f32x4 z4 = {0.f, 0.f, 0.f, 0.f};
  for (int i = 0; i < 4; i++)
    for (int j = 0; j < 4; j++) acc[i][j] = z4;

  for (int kt = 0; kt < K; kt += 64) {
    __syncthreads();
#pragma unroll
    for (int s = 0; s < 2; s++) {
      gl_lds16(Ag0 + kt + s * 32, &As[s * 4096 + t * 8]);
      gl_lds16(Ag1 + kt + s * 32, &As[s * 4096 + 2048 + t * 8]);
      gl_lds16(Bg0 + kt + s * 32, &Bs[s * 4096 + t * 8]);
      gl_lds16(Bg1 + kt + s * 32, &Bs[s * 4096 + 2048 + t * 8]);
    }
    __syncthreads();
#pragma unroll
    for (int s = 0; s < 2; s++) {
      f16x8 af[4], bfr[4];
#pragma unroll
      for (int i = 0; i < 4; i++)
        af[i] = *(const f16x8*)&As[s * 4096 + (m_off + i * 16 + l15) * 32 + qsw * 8];
#pragma unroll
      for (int i = 0; i < 4; i++)
        bfr[i] = *(const f16x8*)&Bs[s * 4096 + (n_off + i * 16 + l15) * 32 + qsw * 8];
#pragma unroll
      for (int mi = 0; mi < 4; mi++)
#pragma unroll
        for (int ni = 0; ni < 4; ni++)
          acc[mi][ni] = __builtin_amdgcn_mfma_f32_16x16x32_f16(af[mi], bfr[ni],
                                                               acc[mi][ni], 0, 0, 0);
    }
  }

  if (MODE == 0) {
#pragma unroll
    for (int mi = 0; mi < 4; mi++) {
      int row = m0 + m_off + mi * 16 + quad * 4;
#pragma unroll
      for (int ni = 0; ni < 4; ni++) {
        int col = n0 + n_off + ni * 16 + l15;
#pragma unroll
        for (int r = 0; r < 4; r++) Cf[(size_t)(row + r) * N + col] = acc[mi][ni][r];
      }
    }
  } else {
    if (n0 < 2 * DM) {  // Q or K block: coalesced writes via LDS transpose
      const int which = n0 / DM;
      const float scl = (which == 0) ? 0.18033688011f : 1.0f;
      __syncthreads();  // all waves done with As/Bs reads
#pragma unroll
      for (int mi = 0; mi < 4; mi++) {
        int ssb = m_off + mi * 16 + quad * 4;
#pragma unroll
        for (int ni = 0; ni < 4; ni++) {
          int col = n_off + ni * 16 + l15;
#pragma unroll
          for (int r = 0; r < 4; r++) {
            int ss = ssb + r;
            // XOR col bits 3-5 with ss bits 0-2: quads land 64B apart -> no
            // bank conflicts; 8-f16 read granules stay contiguous.
            SH[ss * 128 + (col ^ ((ss & 7) << 3))] = f2h(acc[mi][ni][r] * scl);
          }
        }
      }
      __syncthreads();
      const int bb = m0 >> 11, ssbase = m0 & 2047;
      const int h0 = (n0 - which * DM) >> 6;
#pragma unroll
      for (int j = 0; j < 8; j++) {
        int e = j * 256 + t;
        int ss = e >> 4, u = e & 15;       // row 0..127, 16B-unit 0..15
        int h2 = h0 + (u >> 3), kk = (u & 7) * 8;
        f16x8 v = *(const f16x8*)&SH[ss * 128 + ((u * 8) ^ ((ss & 7) << 3))];
        *(f16x8*)&Cq[(size_t)which * HBSD +
                     ((size_t)((h2 * B_ + bb) * S_) + ssbase + ss) * DK + kk] = v;
      }
    } else {  // V block: coalesced V^T via LDS transpose (reuse SH)
      __syncthreads();  // all waves done with As/Bs reads
#pragma unroll
      for (int mi = 0; mi < 4; mi++) {
        int ssb = m_off + mi * 16 + quad * 4;
#pragma unroll
        for (int ni = 0; ni < 4; ni++) {
          int c = n_off + ni * 16 + l15;
          f16* row = &SH[c * 128];
          int swz = (c & 7) << 3;  // XOR ss bits 3-5: spreads the 256B-stride banks
#pragma unroll
          for (int r = 0; r < 4; r++) row[(ssb + r) ^ swz] = f2h(acc[mi][ni][r]);
        }
      }
      __syncthreads();
      const int bb = m0 >> 11, ssbase = m0 & 2047;
      const int hbase = (n0 - 2 * DM) >> 6;
      const int l15t = t & 15, rowg = t >> 4;
#pragma unroll
      for (int j = 0; j < 8; j++) {
        int c = rowg + 16 * j;  // 0..127
        int h2 = hbase + (c >> 6), kk = c & 63;
        f16x8 v = *(const f16x8*)&SH[c * 128 + ((l15t * 8) ^ ((c & 7) << 3))];
        *(f16x8*)&Vt[((size_t)(h2 * B_ + bb) * DK + kk) * S_ + ssbase + l15t * 8] = v;
      }
    }
  }
}

// ---------------- flash attention v11 (verified best): shfl-free softmax ---------
// 768 blocks; bid&7 = XCD; block owns q-tiles qbA=pr, qbB=31-pr of (h,b)=hb —
// 33 job-tiles per block. Pair-staging: 2 kv-tiles per barrier pair.
// Q arrives pre-scaled by log2(e)/8 (GEMM epilogue) so scores are directly in
// log2 units; defer-max check is PER-LANE (no shfls on the fast path; wave-max
// shfls only inside the rare rescale branch); l partial stays per-lane, cross-
// quad combine moved to the epilogue. [R5/R10 measured 62.3-62.7us; v12/v13/v15
// softmax restructures were all neutral-to-negative — do not re-attempt.]
__global__ __launch_bounds__(256, 3) void flash_kernel(const f16* __restrict__ Qg,
                                                       const f16* __restrict__ Kg,
                                                       const f16* __restrict__ Vtg,
                                                       f16* __restrict__ MH) {
  __shared__ __align__(16) f16 Ksh[2][4096];  // [tile][kc2][kv][32] (swizzled)
  __shared__ __align__(16) f16 Vsh[2][4096];  // [tile][kc2][v][32]  (swizzled)
  __shared__ __align__(16) f16 Ps[4][16 * 72];

  const int t = threadIdx.x, lane = t & 63, w = t >> 6;
  const int l15 = lane & 15, quad = lane >> 4;
  const int qsw = quad ^ ((l15 >> 1) & 3);  // swizzled read quad for Ksh/Vsh
  const int bid = blockIdx.x;
  const int xcd = bid & 7, gi = bid >> 3;
  const int hbi = gi % 6, pr = gi / 6;
  const int hb = xcd * 6 + hbi;
  const int qbA = pr, qbB = 31 - pr;
  const int h = hb >> 2, b = hb & 3;
  const size_t base = (size_t)hb * S_ * DK;
  const f16* Qp = Qg + base;
  const f16* Kp = Kg + base;
  const f16* Vp = Vtg + base;  // [d][S_]

  // Q fragments for both jobs, once from global (already ×log2(e)/8)
  f16x8 aqA[2], aqB[2];
  {
    const f16* qa = Qp + (size_t)(qbA * 64 + w * 16 + l15) * DK + quad * 8;
    aqA[0] = *(const f16x8*)(qa);
    aqA[1] = *(const f16x8*)(qa + 32);
    const f16* qb_ = Qp + (size_t)(qbB * 64 + w * 16 + l15) * DK + quad * 8;
    aqB[0] = *(const f16x8*)(qb_);
    aqB[1] = *(const f16x8*)(qb_ + 32);
  }
  const int qlaneA = qbA * 64 + w * 16 + l15;
  const int qlaneB = qbB * 64 + w * 16 + l15;

  // staging source: pre-swizzled column so linear global_load_lds yields the
  // swizzled LDS layout (both-sides-or-neither).
  const int srow = t >> 2, scol = ((t & 3) ^ ((t >> 3) & 3)) * 8;
  const f16* Kst = Kp + (size_t)srow * DK + scol;
  const f16* Vst = Vp + (size_t)srow * S_ + scol;

  float mA = -1e30f, lA = 0.f, mB = -1e30f, lB = 0.f;  // l is per-lane partial
  f32x4 oA[4], oB[4];
  const f32x4 z4 = {0.f, 0.f, 0.f, 0.f};
#pragma unroll
  for (int ni = 0; ni < 4; ni++) { oA[ni] = z4; oB[ni] = z4; }

  auto stage = [&](int buf, int kv0) {
    gl_lds16(Kst + (size_t)kv0 * DK, &Ksh[buf][t * 8]);
    gl_lds16(Kst + (size_t)kv0 * DK + 32, &Ksh[buf][2048 + t * 8]);
    gl_lds16(Vst + kv0, &Vsh[buf][t * 8]);
    gl_lds16(Vst + kv0 + 32, &Vsh[buf][2048 + t * 8]);
  };

  // per-job tile processing
  auto do_job = [&](int buf, const f16x8* aq, float& m_s, float& l_s, f32x4* oacc,
                    int qlane, int kv0, bool diag) {
    f32x4 sa[4];
#pragma unroll
    for (int mi = 0; mi < 4; mi++) {
      f16x8 k0 = *(const f16x8*)&Ksh[buf][(mi * 16 + l15) * 32 + qsw * 8];
      sa[mi] = __builtin_amdgcn_mfma_f32_16x16x32_f16(k0, aq[0], z4, 0, 0, 0);
    }
#pragma unroll
    for (int mi = 0; mi < 4; mi++) {
      f16x8 k1 = *(const f16x8*)&Ksh[buf][2048 + (mi * 16 + l15) * 32 + qsw * 8];
      sa[mi] = __builtin_amdgcn_mfma_f32_16x16x32_f16(k1, aq[1], sa[mi], 0, 0, 0);
    }

    if (diag) {  // diagonal tile: mask kv > q
#pragma unroll
      for (int mi = 0; mi < 4; mi++)
#pragma unroll
        for (int r = 0; r < 4; r++)
          if (kv0 + mi * 16 + quad * 4 + r > qlane) sa[mi][r] = -1e30f;
    }

    // per-lane max of this lane's 16 score elements (already log2-scaled)
    float g0 = max3f(sa[0][0], sa[0][1], sa[0][2]);
    float g1 = max3f(sa[0][3], sa[1][0], sa[1][1]);
    float g2 = max3f(sa[1][2], sa[1][3], sa[2][0]);
    float g3 = max3f(sa[2][1], sa[2][2], sa[2][3]);
    float g4 = max3f(sa[3][0], sa[3][1], sa[3][2]);
    float mx = fmaxf(max3f(g0, g1, g2), max3f(g3, g4, sa[3][3]));
    // defer-max (T13), per-lane check: fast path needs NO cross-lane reduce.
    if (!__all(mx <= m_s + 8.f)) {
      // rare: form the row max (4 quads share a q-row), rescale consistently
      float mr = fmaxf(mx, __shfl_xor(mx, 16));
      mr = fmaxf(mr, __shfl_xor(mr, 32));
      float m2 = fmaxf(m_s, mr);
      float alpha = __builtin_exp2f(m_s - m2);
      l_s *= alpha;
#pragma unroll
      for (int ni = 0; ni < 4; ni++)
#pragma unroll
        for (int r = 0; r < 4; r++) oacc[ni][r] *= alpha;
      m_s = m2;
    }
    const float m2 = m_s;
    float rs = 0.f;
#pragma unroll
    for (int mi = 0; mi < 4; mi++)
#pragma unroll
      for (int r = 0; r < 4; r++) {
        float p = __builtin_exp2f(sa[mi][r] - m2);
        sa[mi][r] = p;
        rs += p;
      }
    l_s += rs;  // per-lane partial; cross-quad combine deferred to epilogue

    // P^T -> Ps[q][kv] (per-wave slice)
#pragma unroll
    for (int mi = 0; mi < 4; mi++) {
      union { h16x2 h2[2]; uint2 u; } pk;
      pk.h2[0] = __builtin_amdgcn_cvt_pkrtz(sa[mi][0], sa[mi][1]);
      pk.h2[1] = __builtin_amdgcn_cvt_pkrtz(sa[mi][2], sa[mi][3]);
      *(uint2*)&Ps[w][l15 * 72 + mi * 16 + quad * 4] = pk.u;
    }

    // O^T += V^T P^T
#pragma unroll
    for (int kc2 = 0; kc2 < 2; kc2++) {
      f16x8 ap = *(const f16x8*)&Ps[w][l15 * 72 + kc2 * 32 + quad * 8];
#pragma unroll
      for (int ni = 0; ni < 4; ni++) {
        f16x8 vf =
            *(const f16x8*)&Vsh[buf][kc2 * 2048 + (ni * 16 + l15) * 32 + qsw * 8];
        oacc[ni] = __builtin_amdgcn_mfma_f32_16x16x32_f16(vf, ap, oacc[ni], 0, 0, 0);
      }
    }
  };

  // pair loop: stage 2 kv-tiles per barrier pair, then process both
  int kt = 0;
  while (kt + 1 <= qbB) {
    __syncthreads();
    stage(0, kt * 64);
    stage(1, kt * 64 + 64);
    __syncthreads();
    do_job(0, aqB, mB, lB, oB, qlaneB, kt * 64, false);
    if (kt <= qbA) do_job(0, aqA, mA, lA, oA, qlaneA, kt * 64, kt == qbA);
    do_job(1, aqB, mB, lB, oB, qlaneB, kt * 64 + 64, kt + 1 == qbB);
    if (kt + 1 <= qbA) do_job(1, aqA, mA, lA, oA, qlaneA, kt * 64 + 64, kt + 1 == qbA);
    kt += 2;
  }
  if (kt <= qbB) {  // odd tail tile
    __syncthreads();
    stage(0, kt * 64);
    __syncthreads();
    do_job(0, aqB, mB, lB, oB, qlaneB, kt * 64, kt == qbB);
    if (kt <= qbA) do_job(0, aqA, mA, lA, oA, qlaneA, kt * 64, kt == qbA);
  }

  // epilogue: combine per-lane l partials across the 4 quads of each q-row,
  // then normalize and write MH[b][q][h*64+v]; v = ni*16+quad*4+r
  {
    float lt = lB;
    lt += __shfl_xor(lt, 16);
    lt += __shfl_xor(lt, 32);
    float linv = 1.0f / lt;
    f16* dst = MH + ((size_t)b * S_ + qlaneB) * DM + h * DK + quad * 4;
#pragma unroll
    for (int ni = 0; ni < 4; ni++) {
      union { f16 hh[4]; uint2 u; } pk;
#pragma unroll
      for (int r = 0; r < 4; r++) pk.hh[r] = f2h(oB[ni][r] * linv);
      *(uint2*)(dst + ni * 16) = pk.u;
    }
  }
  {
    float lt = lA;
    lt += __shfl_xor(lt, 16);
    lt += __shfl_xor(lt, 32);
    float linv = 1.0f / lt;
    f16* dst = MH + ((size_t)b * S_ + qlaneA) * DM + h * DK + quad * 4;
#pragma unroll
    for (int ni = 0; ni < 4; ni++) {
      union { f16 hh[4]; uint2 u; } pk;
#pragma unroll
      for (int r = 0; r < 4; r++) pk.hh[r] = f2h(oA[ni][r] * linv);
      *(uint2*)(dst + ni * 16) = pk.u;
    }
  }
}

// ---------------- launch ----------------

extern "C" void kernel_launch(void* const* d_in, const int* in_sizes, int n_in,
                              void* d_out, int out_size, void* d_ws, size_t ws_size,
                              hipStream_t stream) {
  const float* residual = (const float*)d_in[0];
  const float* WQ = (const float*)d_in[1];
  const float* WK = (const float*)d_in[2];
  const float* WV = (const float*)d_in[3];
  const float* WO = (const float*)d_in[4];
  float* out = (float*)d_out;

  char* ws = (char*)d_ws;
  size_t off = 0;
  auto alloc = [&](size_t bytes) {
    void* p = ws + off;
    off += (bytes + 255) & ~(size_t)255;
    return p;
  };
  f16* xb = (f16*)alloc((size_t)B_ * S_ * DM * 2);   // 12.6 MB
  f16* wqkv = (f16*)alloc((size_t)3 * DM * DM * 2);  // 3.5 MB
  f16* wot = (f16*)alloc((size_t)DM * DM * 2);       // 1.2 MB
  f16* qk = (f16*)alloc(2 * HBSD * 2);               // 25.2 MB (Q,K)
  f16* vt = (f16*)alloc(HBSD * 2);                   // 12.6 MB (V^T)
  f16* mh = (f16*)alloc((size_t)B_ * S_ * DM * 2);   // 12.6 MB

  cast_x_kernel<<<(B_ * S_ * DM / 4 + 255) / 256, 256, 0, stream>>>(residual, xb,
                                                                    B_ * S_ * DM / 4);
  tcast_w_kernel<<<dim3(DM / 64, 4, H_), 256, 0, stream>>>(WQ, WK, WV, WO, wqkv, wot);

  gemm_bt_kernel<1><<<dim3(3 * DM / 128, B_ * S_ / 128), 256, 0, stream>>>(
      xb, wqkv, nullptr, qk, vt, 3 * DM);

  flash_kernel<<<768, 256, 0, stream>>>(qk, qk + HBSD, vt, mh);

  gemm_bt_kernel<0><<<dim3(DM / 128, B_ * S_ / 128), 256, 0, stream>>>(
      mh, wot, out, nullptr, nullptr, DM);
}

// Round 12
// 205.314 us; speedup vs baseline: 1.0201x; 1.0201x over previous
//
#include <hip/hip_runtime.h>

typedef _Float16 f16;
typedef __fp16 h16x2 __attribute__((ext_vector_type(2)));
typedef _Float16 f16x8 __attribute__((ext_vector_type(8)));
typedef float f32x4 __attribute__((ext_vector_type(4)));

#define H_ 12
#define B_ 4
#define S_ 2048
#define DM 768
#define DK 64
#define HBSD ((size_t)H_ * B_ * S_ * DK)

__device__ __forceinline__ f16 f2h(float f) { return (f16)f; }
__device__ __forceinline__ float max3f(float a, float b, float c) {
  return fmaxf(fmaxf(a, b), c);  // clang fuses to v_max3_f32
}

// async global->LDS, 16B per lane. LDS dest must be wave-uniform base + lane*16.
__device__ __forceinline__ void gl_lds16(const f16* g, f16* l) {
  __builtin_amdgcn_global_load_lds(
      (const __attribute__((address_space(1))) void*)g,
      (__attribute__((address_space(3))) void*)l, 16, 0, 0);
}

// ---------------- prep kernels ----------------

__global__ __launch_bounds__(256) void cast_x_kernel(const float* __restrict__ x,
                                                     f16* __restrict__ xb, int n4) {
  int i = blockIdx.x * 256 + threadIdx.x;
  if (i < n4) {
    float4 v = ((const float4*)x)[i];
    union { f16 h[4]; uint2 u; } pk;
    pk.h[0] = f2h(v.x); pk.h[1] = f2h(v.y); pk.h[2] = f2h(v.z); pk.h[3] = f2h(v.w);
    ((uint2*)xb)[i] = pk.u;
  }
}

// Merged weight transpose+cast (one launch):
// which<3: W_{which}[h][m][c] -> Wt[(which*768 + h*64 + c)][m]
// which==3: WO[n][d] -> Wot[d][n]
__global__ __launch_bounds__(256) void tcast_w_kernel(const float* __restrict__ WQ,
                                                      const float* __restrict__ WK,
                                                      const float* __restrict__ WV,
                                                      const float* __restrict__ WO,
                                                      f16* __restrict__ Wt,
                                                      f16* __restrict__ Wot) {
  __shared__ float L[64][65];
  const int which = blockIdx.y;
  const int t = threadIdx.x;
  const int lr = t >> 2, lc = (t & 3) * 16;
  const float* ip;
  if (which < 3) {
    const int m0 = blockIdx.x * 64, h = blockIdx.z;
    const float* in = (which == 0 ? WQ : which == 1 ? WK : WV) + (size_t)h * DM * DK;
    ip = in + (size_t)(m0 + lr) * DK + lc;
  } else {
    const int n0 = blockIdx.x * 64, d0 = blockIdx.z * 64;
    ip = WO + (size_t)(n0 + lr) * DM + d0 + lc;
  }
#pragma unroll
  for (int i = 0; i < 4; i++) {
    float4 v = *(const float4*)(ip + i * 4);
    L[lr][lc + i * 4 + 0] = v.x;
    L[lr][lc + i * 4 + 1] = v.y;
    L[lr][lc + i * 4 + 2] = v.z;
    L[lr][lc + i * 4 + 3] = v.w;
  }
  __syncthreads();
  const int oc = t >> 2, om = (t & 3) * 16;
  union { f16 hh[16]; uint4 u[2]; } pk;
#pragma unroll
  for (int jx = 0; jx < 16; jx++) pk.hh[jx] = f2h(L[om + jx][oc]);
  f16* op;
  if (which < 3) {
    const int m0 = blockIdx.x * 64, h = blockIdx.z;
    op = Wt + ((size_t)which * DM + h * DK + oc) * DM + m0 + om;
  } else {
    const int n0 = blockIdx.x * 64, d0 = blockIdx.z * 64;
    op = Wot + (size_t)(d0 + oc) * DM + n0 + om;
  }
  *(uint4*)op = pk.u[0];
  *(uint4*)(op + 8) = pk.u[1];
}

// ---------------- GEMM, BK=64 2-slab: C[M,N] = A[M,K] * Bt[N,K]^T ----------------
// MODE==1 (x->QKV): BM=128, identical to R11 (LDS-transpose epilogues, XCD swz).
// MODE==0 (mh->out): v17 BM=64 tile -> grid 128x6 = 768 blocks = EXACTLY 3/CU
// (was 384 = 1.5/CU -> ~33% makespan quantization loss). 4 waves each own a
// 64x32 column slice (acc[4][2]); A-staging halves; LDS 24KB.
template <int MODE>
__global__ __launch_bounds__(256) void gemm_bt_kernel(const f16* __restrict__ A,
                                                      const f16* __restrict__ Bt,
                                                      float* __restrict__ Cf,
                                                      f16* __restrict__ Cq,
                                                      f16* __restrict__ Vt, int N) {
  constexpr int K = 768;
  constexpr int BM = (MODE == 0 ? 64 : 128);
  constexpr int NI = (MODE == 0 ? 2 : 4);        // acc column frags per wave
  constexpr int ASLAB = (MODE == 0 ? 2048 : 4096);  // f16 per A slab
  __shared__ __align__(16) f16 SH[16384];  // As | Bs; reused as transpose buffer
  f16* As = SH;
  f16* Bs = SH + 2 * ASLAB;
  const int t = threadIdx.x;
  const int nbx = gridDim.x, nwg = nbx * gridDim.y;
  const int d = blockIdx.y * nbx + blockIdx.x;
  const int wg = (d & 7) * (nwg >> 3) + (d >> 3);  // bijective (nwg%8==0)
  const int m0 = (wg / nbx) * BM, n0 = (wg % nbx) * 128;
  const int lane = t & 63, wave = t >> 6;
  const int l15 = lane & 15, quad = lane >> 4;
  const int qsw = quad ^ ((l15 >> 1) & 3);  // swizzled read quad
  const int m_off = (MODE == 0) ? 0 : (wave & 1) * 64;
  const int n_off = (MODE == 0) ? wave * 32 : (wave >> 1) * 64;
  const int r0 = t >> 2, ko = ((t & 3) ^ ((t >> 3) & 3)) * 8;  // swizzled source col
  const f16* Ag0 = A + (size_t)(m0 + r0) * K + ko;
  const f16* Ag1 = A + (size_t)(m0 + r0 + 64) * K + ko;  // MODE==1 only
  const f16* Bg0 = Bt + (size_t)(n0 + r0) * K + ko;
  const f16* Bg1 = Bt + (size_t)(n0 + r0 + 64) * K + ko;

  f32x4 acc[4][NI];
  const f32x4 z4 = {0.f, 0.f, 0.f, 0.f};
  for (int i = 0; i < 4; i++)
    for (int j = 0; j < NI; j++) acc[i][j] = z4;

  for (int kt = 0; kt < K; kt += 64) {
    __syncthreads();
#pragma unroll
    for (int s = 0; s < 2; s++) {
      if constexpr (MODE == 1) {
        gl_lds16(Ag0 + kt + s * 32, &As[s * ASLAB + t * 8]);
        gl_lds16(Ag1 + kt + s * 32, &As[s * ASLAB + 2048 + t * 8]);
      } else {
        gl_lds16(Ag0 + kt + s * 32, &As[s * ASLAB + t * 8]);
      }
      gl_lds16(Bg0 + kt + s * 32, &Bs[s * 4096 + t * 8]);
      gl_lds16(Bg1 + kt + s * 32, &Bs[s * 4096 + 2048 + t * 8]);
    }
    __syncthreads();
#pragma unroll
    for (int s = 0; s < 2; s++) {
      f16x8 af[4], bfr[NI];
#pragma unroll
      for (int i = 0; i < 4; i++)
        af[i] =
            *(const f16x8*)&As[s * ASLAB + (m_off + i * 16 + l15) * 32 + qsw * 8];
#pragma unroll
      for (int i = 0; i < NI; i++)
        bfr[i] =
            *(const f16x8*)&Bs[s * 4096 + (n_off + i * 16 + l15) * 32 + qsw * 8];
#pragma unroll
      for (int mi = 0; mi < 4; mi++)
#pragma unroll
        for (int ni = 0; ni < NI; ni++)
          acc[mi][ni] = __builtin_amdgcn_mfma_f32_16x16x32_f16(af[mi], bfr[ni],
                                                               acc[mi][ni], 0, 0, 0);
    }
  }

  if constexpr (MODE == 0) {
#pragma unroll
    for (int mi = 0; mi < 4; mi++) {
      int row = m0 + mi * 16 + quad * 4;
#pragma unroll
      for (int ni = 0; ni < NI; ni++) {
        int col = n0 + n_off + ni * 16 + l15;
#pragma unroll
        for (int r = 0; r < 4; r++) Cf[(size_t)(row + r) * N + col] = acc[mi][ni][r];
      }
    }
  } else {
    if (n0 < 2 * DM) {  // Q or K block: coalesced writes via LDS transpose
      const int which = n0 / DM;
      const float scl = (which == 0) ? 0.18033688011f : 1.0f;
      __syncthreads();  // all waves done with As/Bs reads
#pragma unroll
      for (int mi = 0; mi < 4; mi++) {
        int ssb = m_off + mi * 16 + quad * 4;
#pragma unroll
        for (int ni = 0; ni < 4; ni++) {
          int col = n_off + ni * 16 + l15;
#pragma unroll
          for (int r = 0; r < 4; r++) {
            int ss = ssb + r;
            // XOR col bits 3-5 with ss bits 0-2: quads land 64B apart -> no
            // bank conflicts; 8-f16 read granules stay contiguous.
            SH[ss * 128 + (col ^ ((ss & 7) << 3))] = f2h(acc[mi][ni][r] * scl);
          }
        }
      }
      __syncthreads();
      const int bb = m0 >> 11, ssbase = m0 & 2047;
      const int h0 = (n0 - which * DM) >> 6;
#pragma unroll
      for (int j = 0; j < 8; j++) {
        int e = j * 256 + t;
        int ss = e >> 4, u = e & 15;       // row 0..127, 16B-unit 0..15
        int h2 = h0 + (u >> 3), kk = (u & 7) * 8;
        f16x8 v = *(const f16x8*)&SH[ss * 128 + ((u * 8) ^ ((ss & 7) << 3))];
        *(f16x8*)&Cq[(size_t)which * HBSD +
                     ((size_t)((h2 * B_ + bb) * S_) + ssbase + ss) * DK + kk] = v;
      }
    } else {  // V block: coalesced V^T via LDS transpose (reuse SH)
      __syncthreads();  // all waves done with As/Bs reads
#pragma unroll
      for (int mi = 0; mi < 4; mi++) {
        int ssb = m_off + mi * 16 + quad * 4;
#pragma unroll
        for (int ni = 0; ni < 4; ni++) {
          int c = n_off + ni * 16 + l15;
          f16* row = &SH[c * 128];
          int swz = (c & 7) << 3;  // XOR ss bits 3-5: spreads the 256B-stride banks
#pragma unroll
          for (int r = 0; r < 4; r++) row[(ssb + r) ^ swz] = f2h(acc[mi][ni][r]);
        }
      }
      __syncthreads();
      const int bb = m0 >> 11, ssbase = m0 & 2047;
      const int hbase = (n0 - 2 * DM) >> 6;
      const int l15t = t & 15, rowg = t >> 4;
#pragma unroll
      for (int j = 0; j < 8; j++) {
        int c = rowg + 16 * j;  // 0..127
        int h2 = hbase + (c >> 6), kk = c & 63;
        f16x8 v = *(const f16x8*)&SH[c * 128 + ((l15t * 8) ^ ((c & 7) << 3))];
        *(f16x8*)&Vt[((size_t)(h2 * B_ + bb) * DK + kk) * S_ + ssbase + l15t * 8] = v;
      }
    }
  }
}

// ---------------- flash attention v11 (verified best): shfl-free softmax ---------
// 768 blocks; bid&7 = XCD; block owns q-tiles qbA=pr, qbB=31-pr of (h,b)=hb —
// 33 job-tiles per block. Pair-staging: 2 kv-tiles per barrier pair.
// Q arrives pre-scaled by log2(e)/8 (GEMM epilogue) so scores are directly in
// log2 units; defer-max check is PER-LANE (no shfls on the fast path; wave-max
// shfls only inside the rare rescale branch); l partial stays per-lane, cross-
// quad combine moved to the epilogue. [R5/R10 measured 62.3-62.7us; v12/v13/v15
// softmax restructures were all neutral-to-negative — do not re-attempt.]
__global__ __launch_bounds__(256, 3) void flash_kernel(const f16* __restrict__ Qg,
                                                       const f16* __restrict__ Kg,
                                                       const f16* __restrict__ Vtg,
                                                       f16* __restrict__ MH) {
  __shared__ __align__(16) f16 Ksh[2][4096];  // [tile][kc2][kv][32] (swizzled)
  __shared__ __align__(16) f16 Vsh[2][4096];  // [tile][kc2][v][32]  (swizzled)
  __shared__ __align__(16) f16 Ps[4][16 * 72];

  const int t = threadIdx.x, lane = t & 63, w = t >> 6;
  const int l15 = lane & 15, quad = lane >> 4;
  const int qsw = quad ^ ((l15 >> 1) & 3);  // swizzled read quad for Ksh/Vsh
  const int bid = blockIdx.x;
  const int xcd = bid & 7, gi = bid >> 3;
  const int hbi = gi % 6, pr = gi / 6;
  const int hb = xcd * 6 + hbi;
  const int qbA = pr, qbB = 31 - pr;
  const int h = hb >> 2, b = hb & 3;
  const size_t base = (size_t)hb * S_ * DK;
  const f16* Qp = Qg + base;
  const f16* Kp = Kg + base;
  const f16* Vp = Vtg + base;  // [d][S_]

  // Q fragments for both jobs, once from global (already ×log2(e)/8)
  f16x8 aqA[2], aqB[2];
  {
    const f16* qa = Qp + (size_t)(qbA * 64 + w * 16 + l15) * DK + quad * 8;
    aqA[0] = *(const f16x8*)(qa);
    aqA[1] = *(const f16x8*)(qa + 32);
    const f16* qb_ = Qp + (size_t)(qbB * 64 + w * 16 + l15) * DK + quad * 8;
    aqB[0] = *(const f16x8*)(qb_);
    aqB[1] = *(const f16x8*)(qb_ + 32);
  }
  const int qlaneA = qbA * 64 + w * 16 + l15;
  const int qlaneB = qbB * 64 + w * 16 + l15;

  // staging source: pre-swizzled column so linear global_load_lds yields the
  // swizzled LDS layout (both-sides-or-neither).
  const int srow = t >> 2, scol = ((t & 3) ^ ((t >> 3) & 3)) * 8;
  const f16* Kst = Kp + (size_t)srow * DK + scol;
  const f16* Vst = Vp + (size_t)srow * S_ + scol;

  float mA = -1e30f, lA = 0.f, mB = -1e30f, lB = 0.f;  // l is per-lane partial
  f32x4 oA[4], oB[4];
  const f32x4 z4 = {0.f, 0.f, 0.f, 0.f};
#pragma unroll
  for (int ni = 0; ni < 4; ni++) { oA[ni] = z4; oB[ni] = z4; }

  auto stage = [&](int buf, int kv0) {
    gl_lds16(Kst + (size_t)kv0 * DK, &Ksh[buf][t * 8]);
    gl_lds16(Kst + (size_t)kv0 * DK + 32, &Ksh[buf][2048 + t * 8]);
    gl_lds16(Vst + kv0, &Vsh[buf][t * 8]);
    gl_lds16(Vst + kv0 + 32, &Vsh[buf][2048 + t * 8]);
  };

  // per-job tile processing
  auto do_job = [&](int buf, const f16x8* aq, float& m_s, float& l_s, f32x4* oacc,
                    int qlane, int kv0, bool diag) {
    f32x4 sa[4];
#pragma unroll
    for (int mi = 0; mi < 4; mi++) {
      f16x8 k0 = *(const f16x8*)&Ksh[buf][(mi * 16 + l15) * 32 + qsw * 8];
      sa[mi] = __builtin_amdgcn_mfma_f32_16x16x32_f16(k0, aq[0], z4, 0, 0, 0);
    }
#pragma unroll
    for (int mi = 0; mi < 4; mi++) {
      f16x8 k1 = *(const f16x8*)&Ksh[buf][2048 + (mi * 16 + l15) * 32 + qsw * 8];
      sa[mi] = __builtin_amdgcn_mfma_f32_16x16x32_f16(k1, aq[1], sa[mi], 0, 0, 0);
    }

    if (diag) {  // diagonal tile: mask kv > q
#pragma unroll
      for (int mi = 0; mi < 4; mi++)
#pragma unroll
        for (int r = 0; r < 4; r++)
          if (kv0 + mi * 16 + quad * 4 + r > qlane) sa[mi][r] = -1e30f;
    }

    // per-lane max of this lane's 16 score elements (already log2-scaled)
    float g0 = max3f(sa[0][0], sa[0][1], sa[0][2]);
    float g1 = max3f(sa[0][3], sa[1][0], sa[1][1]);
    float g2 = max3f(sa[1][2], sa[1][3], sa[2][0]);
    float g3 = max3f(sa[2][1], sa[2][2], sa[2][3]);
    float g4 = max3f(sa[3][0], sa[3][1], sa[3][2]);
    float mx = fmaxf(max3f(g0, g1, g2), max3f(g3, g4, sa[3][3]));
    // defer-max (T13), per-lane check: fast path needs NO cross-lane reduce.
    if (!__all(mx <= m_s + 8.f)) {
      // rare: form the row max (4 quads share a q-row), rescale consistently
      float mr = fmaxf(mx, __shfl_xor(mx, 16));
      mr = fmaxf(mr, __shfl_xor(mr, 32));
      float m2 = fmaxf(m_s, mr);
      float alpha = __builtin_exp2f(m_s - m2);
      l_s *= alpha;
#pragma unroll
      for (int ni = 0; ni < 4; ni++)
#pragma unroll
        for (int r = 0; r < 4; r++) oacc[ni][r] *= alpha;
      m_s = m2;
    }
    const float m2 = m_s;
    float rs = 0.f;
#pragma unroll
    for (int mi = 0; mi < 4; mi++)
#pragma unroll
      for (int r = 0; r < 4; r++) {
        float p = __builtin_exp2f(sa[mi][r] - m2);
        sa[mi][r] = p;
        rs += p;
      }
    l_s += rs;  // per-lane partial; cross-quad combine deferred to epilogue

    // P^T -> Ps[q][kv] (per-wave slice)
#pragma unroll
    for (int mi = 0; mi < 4; mi++) {
      union { h16x2 h2[2]; uint2 u; } pk;
      pk.h2[0] = __builtin_amdgcn_cvt_pkrtz(sa[mi][0], sa[mi][1]);
      pk.h2[1] = __builtin_amdgcn_cvt_pkrtz(sa[mi][2], sa[mi][3]);
      *(uint2*)&Ps[w][l15 * 72 + mi * 16 + quad * 4] = pk.u;
    }

    // O^T += V^T P^T
#pragma unroll
    for (int kc2 = 0; kc2 < 2; kc2++) {
      f16x8 ap = *(const f16x8*)&Ps[w][l15 * 72 + kc2 * 32 + quad * 8];
#pragma unroll
      for (int ni = 0; ni < 4; ni++) {
        f16x8 vf =
            *(const f16x8*)&Vsh[buf][kc2 * 2048 + (ni * 16 + l15) * 32 + qsw * 8];
        oacc[ni] = __builtin_amdgcn_mfma_f32_16x16x32_f16(vf, ap, oacc[ni], 0, 0, 0);
      }
    }
  };

  // pair loop: stage 2 kv-tiles per barrier pair, then process both
  int kt = 0;
  while (kt + 1 <= qbB) {
    __syncthreads();
    stage(0, kt * 64);
    stage(1, kt * 64 + 64);
    __syncthreads();
    do_job(0, aqB, mB, lB, oB, qlaneB, kt * 64, false);
    if (kt <= qbA) do_job(0, aqA, mA, lA, oA, qlaneA, kt * 64, kt == qbA);
    do_job(1, aqB, mB, lB, oB, qlaneB, kt * 64 + 64, kt + 1 == qbB);
    if (kt + 1 <= qbA) do_job(1, aqA, mA, lA, oA, qlaneA, kt * 64 + 64, kt + 1 == qbA);
    kt += 2;
  }
  if (kt <= qbB) {  // odd tail tile
    __syncthreads();
    stage(0, kt * 64);
    __syncthreads();
    do_job(0, aqB, mB, lB, oB, qlaneB, kt * 64, kt == qbB);
    if (kt <= qbA) do_job(0, aqA, mA, lA, oA, qlaneA, kt * 64, kt == qbA);
  }

  // epilogue: combine per-lane l partials across the 4 quads of each q-row,
  // then normalize and write MH[b][q][h*64+v]; v = ni*16+quad*4+r
  {
    float lt = lB;
    lt += __shfl_xor(lt, 16);
    lt += __shfl_xor(lt, 32);
    float linv = 1.0f / lt;
    f16* dst = MH + ((size_t)b * S_ + qlaneB) * DM + h * DK + quad * 4;
#pragma unroll
    for (int ni = 0; ni < 4; ni++) {
      union { f16 hh[4]; uint2 u; } pk;
#pragma unroll
      for (int r = 0; r < 4; r++) pk.hh[r] = f2h(oB[ni][r] * linv);
      *(uint2*)(dst + ni * 16) = pk.u;
    }
  }
  {
    float lt = lA;
    lt += __shfl_xor(lt, 16);
    lt += __shfl_xor(lt, 32);
    float linv = 1.0f / lt;
    f16* dst = MH + ((size_t)b * S_ + qlaneA) * DM + h * DK + quad * 4;
#pragma unroll
    for (int ni = 0; ni < 4; ni++) {
      union { f16 hh[4]; uint2 u; } pk;
#pragma unroll
      for (int r = 0; r < 4; r++) pk.hh[r] = f2h(oA[ni][r] * linv);
      *(uint2*)(dst + ni * 16) = pk.u;
    }
  }
}

// ---------------- launch ----------------

extern "C" void kernel_launch(void* const* d_in, const int* in_sizes, int n_in,
                              void* d_out, int out_size, void* d_ws, size_t ws_size,
                              hipStream_t stream) {
  const float* residual = (const float*)d_in[0];
  const float* WQ = (const float*)d_in[1];
  const float* WK = (const float*)d_in[2];
  const float* WV = (const float*)d_in[3];
  const float* WO = (const float*)d_in[4];
  float* out = (float*)d_out;

  char* ws = (char*)d_ws;
  size_t off = 0;
  auto alloc = [&](size_t bytes) {
    void* p = ws + off;
    off += (bytes + 255) & ~(size_t)255;
    return p;
  };
  f16* xb = (f16*)alloc((size_t)B_ * S_ * DM * 2);   // 12.6 MB
  f16* wqkv = (f16*)alloc((size_t)3 * DM * DM * 2);  // 3.5 MB
  f16* wot = (f16*)alloc((size_t)DM * DM * 2);       // 1.2 MB
  f16* qk = (f16*)alloc(2 * HBSD * 2);               // 25.2 MB (Q,K)
  f16* vt = (f16*)alloc(HBSD * 2);                   // 12.6 MB (V^T)
  f16* mh = (f16*)alloc((size_t)B_ * S_ * DM * 2);   // 12.6 MB

  cast_x_kernel<<<(B_ * S_ * DM / 4 + 255) / 256, 256, 0, stream>>>(residual, xb,
                                                                    B_ * S_ * DM / 4);
  tcast_w_kernel<<<dim3(DM / 64, 4, H_), 256, 0, stream>>>(WQ, WK, WV, WO, wqkv, wot);

  gemm_bt_kernel<1><<<dim3(3 * DM / 128, B_ * S_ / 128), 256, 0, stream>>>(
      xb, wqkv, nullptr, qk, vt, 3 * DM);

  flash_kernel<<<768, 256, 0, stream>>>(qk, qk + HBSD, vt, mh);

  gemm_bt_kernel<0><<<dim3(DM / 128, B_ * S_ / 64), 256, 0, stream>>>(
      mh, wot, out, nullptr, nullptr, DM);
}